// Round 4
// baseline (694.181 us; speedup 1.0000x reference)
//
#include <hip/hip_runtime.h>
#include <math.h>

#define NND 50000
#define DEG 16

typedef __attribute__((ext_vector_type(8))) short short8v;
typedef __attribute__((ext_vector_type(4))) float float4v;

// ---- workspace layout (bytes) ----
#define OFF_HPRE 0ULL            // N x 64 f32
#define OFF_PROJ 12800000ULL     // 4 x N x 64 f32
#define OFF_XB   64000000ULL     // N x 128 bf16
#define OFF_HBA  76800000ULL     // N x 128 bf16
#define OFF_HBB  89600000ULL     // N x 128 bf16
#define OFF_IDX  102400000ULL    // 5*N int
#define OFF_CUR  103400192ULL    // N int
#define OFF_BQF  103600384ULL    // 4y x 8c x 8ct x 64 x 8 bf16 = 256 KB
#define OFF_WOF  103862528ULL    // 4c x 8ct x 64 x 8 bf16 = 32 KB
#define WS_NEED  103895296ULL

__device__ __forceinline__ float sigf(float x){ return 1.0f/(1.0f + expf(-x)); }
__device__ __forceinline__ unsigned short f2bf(float f){
    unsigned int u = __float_as_uint(f);
    u += 0x7FFFu + ((u >> 16) & 1u);
    return (unsigned short)(u >> 16);
}
__device__ __forceinline__ float bf2f(unsigned short h){
    return __uint_as_float(((unsigned int)h) << 16);
}

__global__ __launch_bounds__(256) void k_iota(int* __restrict__ cur, int* __restrict__ idx0){
    int i = blockIdx.x*256 + threadIdx.x;
    if (i < NND){ cur[i] = i; idx0[i] = i; }
}

// ---------------- walk phase (fp32, argmax determinism) ----------------
// All 5 projections in one pass: out_y(N x 64) = A @ W1[y*128:(y+1)*128] (+b1 if y==0)
// A staged once per k-chunk; acc[5]; FMA order per output identical to split kernels.
__global__ __launch_bounds__(256,2) void k_projall(const float* __restrict__ A,
    const float* __restrict__ W1, const float* __restrict__ b1,
    float* __restrict__ hpre, float* __restrict__ proj)
{
    __shared__ float Al[64][33];
    __shared__ float Bl[5][32][68];
    const int tid = threadIdx.x;
    const int row0 = blockIdx.x << 6;
    const int row_t = tid >> 4, col_t = tid & 15;
    float4 acc[5][4];
#pragma unroll
    for (int y=0;y<5;y++)
#pragma unroll
        for (int i=0;i<4;i++) acc[y][i] = make_float4(0.f,0.f,0.f,0.f);
    for (int k0 = 0; k0 < 128; k0 += 32){
#pragma unroll
        for (int r=0;r<2;r++){
            int am = (tid>>3) + (r<<5);
            int ak = (tid&7) << 2;
            int gr = row0 + am; if (gr >= NND) gr = NND-1;
            float4 v = *(const float4*)(A + (size_t)gr*128 + k0 + ak);
            Al[am][ak] = v.x; Al[am][ak+1] = v.y; Al[am][ak+2] = v.z; Al[am][ak+3] = v.w;
        }
#pragma unroll
        for (int r=0;r<10;r++){
            int p = (r<<8) + tid;          // p in [0, 2560)
            int y = p >> 9, rem = p & 511;
            int bk = rem >> 4, bc = (rem & 15) << 2;
            *(float4*)(&Bl[y][bk][bc]) = *(const float4*)(W1 + ((size_t)(y*128 + k0 + bk))*64 + bc);
        }
        __syncthreads();
#pragma unroll 4
        for (int k=0;k<32;k++){
            float a[4];
#pragma unroll
            for (int i=0;i<4;i++) a[i] = Al[(row_t<<2)+i][k];
#pragma unroll
            for (int y=0;y<5;y++){
                float4 b = *(const float4*)(&Bl[y][k][col_t<<2]);
#pragma unroll
                for (int i=0;i<4;i++){
                    acc[y][i].x = fmaf(a[i], b.x, acc[y][i].x);
                    acc[y][i].y = fmaf(a[i], b.y, acc[y][i].y);
                    acc[y][i].z = fmaf(a[i], b.z, acc[y][i].z);
                    acc[y][i].w = fmaf(a[i], b.w, acc[y][i].w);
                }
            }
        }
        __syncthreads();
    }
    float4 bb = *(const float4*)(b1 + (col_t<<2));
#pragma unroll
    for (int y=0;y<5;y++){
        float* dst = (y == 0) ? hpre : (proj + (size_t)(y-1)*NND*64);
#pragma unroll
        for (int i=0;i<4;i++){
            int gr = row0 + (row_t<<2) + i;
            if (gr < NND){
                float4 o = acc[y][i];
                if (y == 0){ o.x += bb.x; o.y += bb.y; o.z += bb.z; o.w += bb.w; }
                *(float4*)(dst + (size_t)gr*64 + (col_t<<2)) = o;
            }
        }
    }
}

__global__ __launch_bounds__(256) void k_walk(float* __restrict__ hpre,
    const float* __restrict__ proj, const int* __restrict__ dst,
    const float* __restrict__ W2, const float* __restrict__ b2,
    const float* __restrict__ noi, int* __restrict__ cur,
    int* __restrict__ idxo)
{
    __shared__ float hp_l[1024];
    __shared__ float w2_l[64];
    __shared__ int   nv_l[16];
    const int tid = threadIdx.x;
    const int nl = tid >> 4, d = tid & 15;
    const int gi0 = blockIdx.x << 4;
    const int gi = gi0 + nl;
    *(float4*)(hp_l + (tid<<2)) = *(const float4*)(hpre + ((size_t)gi0<<6) + (tid<<2));
    if (tid < 64) w2_l[tid] = W2[tid];
    __syncthreads();
    const int ci  = cur[gi];
    const int nbr = dst[ci*DEG + d];
    float lp = b2[0];
    const float* pj = proj + ((size_t)nbr<<6);
    const float* hh = hp_l + (nl<<6);
#pragma unroll
    for (int h=0; h<64; h+=4){
        float4 p4 = *(const float4*)(pj + h);
        float4 h4 = *(const float4*)(hh + h);
        float4 w4 = *(const float4*)(w2_l + h);
        lp = fmaf(fmaxf(h4.x+p4.x,0.f), w4.x, lp);
        lp = fmaf(fmaxf(h4.y+p4.y,0.f), w4.y, lp);
        lp = fmaf(fmaxf(h4.z+p4.z,0.f), w4.z, lp);
        lp = fmaf(fmaxf(h4.w+p4.w,0.f), w4.w, lp);
    }
    float mx = lp;
#pragma unroll
    for (int off=8; off; off>>=1) mx = fmaxf(mx, __shfl_xor(mx, off, 16));
    float s = expf(lp - mx);
#pragma unroll
    for (int off=8; off; off>>=1) s += __shfl_xor(s, off, 16);
    float p = expf(lp - mx - logf(s)) + noi[((size_t)gi<<4) + d];
    float bv = p; int bi = d;
#pragma unroll
    for (int off=8; off; off>>=1){
        float ov = __shfl_xor(bv, off, 16);
        int   oi = __shfl_xor(bi, off, 16);
        if (ov > bv || (ov == bv && oi < bi)){ bv = ov; bi = oi; }
    }
    int sn = __shfl(nbr, bi, 16);
    if (d == 0){ cur[gi] = sn; idxo[gi] = sn; nv_l[nl] = sn; }
    __syncthreads();
    const int n2 = tid >> 4;
    const int h4i = (tid & 15) << 2;
    const int v = nv_l[n2];
    float4 u  = *(const float4*)(proj + ((size_t)v<<6) + h4i);
    float4 hp = *(const float4*)(hp_l + (n2<<6) + h4i);
    hp.x += u.x; hp.y += u.y; hp.z += u.z; hp.w += u.w;
    *(float4*)(hpre + ((size_t)(gi0+n2)<<6) + h4i) = hp;
}

// ---------------- pack kernels ----------------
__global__ __launch_bounds__(256) void k_pack_x(const float* __restrict__ na,
    unsigned short* __restrict__ Xb)
{
    int i = blockIdx.x*256 + threadIdx.x;
    if (i < NND*32){
        float4 v = *(const float4*)(na + (size_t)i*4);
        unsigned long long pk = (unsigned long long)f2bf(v.x)
            | ((unsigned long long)f2bf(v.y) << 16)
            | ((unsigned long long)f2bf(v.z) << 32)
            | ((unsigned long long)f2bf(v.w) << 48);
        *(unsigned long long*)(Xb + (size_t)i*4) = pk;
    }
}

// BqF[y][c][ct][lane][8]: gate-blocked, MFMA-16x16x32 B-frag order.
// ct = gate*2 + jh; col j = y*32 + jh*16 + (lane&15); k = c*32 + (lane>>4)*8 + jj.
__global__ __launch_bounds__(256) void k_pack_bqf(const float* __restrict__ Wx,
    const float* __restrict__ Wh, unsigned short* __restrict__ BqF)
{
    int i = blockIdx.x*256 + threadIdx.x;  // 131072
    int jj = i & 7, lane = (i>>3)&63, ct = (i>>9)&7, c = (i>>12)&7, y = i>>15;
    int g = ct>>1, jh = ct&1, mm = lane&15, quad = lane>>4;
    int jg = (y<<5) + (jh<<4) + mm;
    int k = (c<<5) + (quad<<3) + jj;
    float v = 0.f;
    if (k < 128){
        if (g < 3) v = Wh[k*384 + g*128 + jg];
    } else {
        int kk = k - 128;
        if (g == 0)      v = Wx[kk*384 + jg];
        else if (g == 1) v = Wx[kk*384 + 128 + jg];
        else if (g == 3) v = Wx[kk*384 + 256 + jg];
    }
    BqF[i] = f2bf(v);
}

__global__ __launch_bounds__(256) void k_pack_wof(const float* __restrict__ Wo,
    unsigned short* __restrict__ WoF)
{
    int i = blockIdx.x*256 + threadIdx.x;  // 16384
    int jj = i & 7, lane = (i>>3)&63, ct = (i>>9)&7, c = i>>12;
    int n = (ct<<4) + (lane&15);
    int k = (c<<5) + ((lane>>4)<<3) + jj;
    WoF[i] = f2bf(Wo[k*128 + n]);
}

// ---------------- GRU step v4: barrier-free, all-register A ----------------
// grid (782), block 256 = 4 waves x 16 rows. Each wave: 16 rows x 512 packed
// cols, K=256. A-frags (h rows + x gather) preloaded to 32 VGPRs; B streamed
// from L2-resident BqF in coalesced 1KB wave-reads. No LDS, no barriers.
__global__ __launch_bounds__(256,2) void k_gruM(
    const unsigned short* __restrict__ hb_in,
    const unsigned short* __restrict__ Xb,
    const unsigned short* __restrict__ BqF,
    const float* __restrict__ bx, const float* __restrict__ bh,
    const int* __restrict__ xidx,
    unsigned short* __restrict__ hb_out, const int first)
{
    const int tid = threadIdx.x;
    const int w = tid >> 6, lane = tid & 63;
    const int m = lane & 15, quad = lane >> 4;
    const int row0 = blockIdx.x << 6;
    int myrow = row0 + (w<<4) + m; if (myrow >= NND) myrow = NND-1;
    const int xr = xidx[myrow];
    const unsigned short* xrow = Xb + (size_t)xr*128;
    const unsigned short* hrow = hb_in + (size_t)myrow*128;
    short8v afr[8];
#pragma unroll
    for (int c=0;c<4;c++)
        afr[4+c] = *(const short8v*)(xrow + (c<<5) + (quad<<3));
    if (!first){
#pragma unroll
        for (int c=0;c<4;c++)
            afr[c] = *(const short8v*)(hrow + (c<<5) + (quad<<3));
    } else {
        short8v z = {0,0,0,0,0,0,0,0};
#pragma unroll
        for (int c=0;c<4;c++) afr[c] = z;   // 0*b contributes exact 0
    }
    float4v zero = {0.f,0.f,0.f,0.f};
    float4v acc[32];
#pragma unroll
    for (int i=0;i<32;i++) acc[i] = zero;
#pragma unroll
    for (int c=0;c<8;c++){
#pragma unroll
        for (int y=0;y<4;y++){
#pragma unroll
            for (int ct=0;ct<8;ct++){
                short8v bf = *(const short8v*)(BqF + ((((size_t)y*8 + c)*8 + ct)*64 + lane)*8);
                acc[y*8+ct] = __builtin_amdgcn_mfma_f32_16x16x32_bf16(afr[c], bf, acc[y*8+ct], 0,0,0);
            }
        }
    }
    // in-lane epilogue: gates r,z,hn,xn in acc[y*8 + g*2 + jh], same lane
#pragma unroll
    for (int y=0;y<4;y++){
#pragma unroll
        for (int jh=0; jh<2; jh++){
            const int j = (y<<5) + (jh<<4) + m;
            const float brr = bx[j]       + bh[j];
            const float bzz = bx[128 + j] + bh[128 + j];
            const float bxn = bx[256 + j];
            const float bhn = bh[256 + j];
#pragma unroll
            for (int r4=0; r4<4; r4++){
                int row = row0 + (w<<4) + (quad<<2) + r4;
                if (row < NND){
                    float rg = sigf(acc[y*8+jh][r4] + brr);
                    float zg = sigf(acc[y*8+2+jh][r4] + bzz);
                    float ng = tanhf(acc[y*8+6+jh][r4] + bxn + rg*(acc[y*8+4+jh][r4] + bhn));
                    float hp = first ? 0.f : bf2f(hb_in[(size_t)row*128 + j]);
                    hb_out[(size_t)row*128 + j] = f2bf((1.f - zg)*ng + zg*hp);
                }
            }
        }
    }
}

// out = hb @ Wo + bo, barrier-free, K=128, 128 cols
__global__ __launch_bounds__(256,2) void k_outM(
    const unsigned short* __restrict__ hb,
    const unsigned short* __restrict__ WoF,
    const float* __restrict__ bo, float* __restrict__ out)
{
    const int tid = threadIdx.x;
    const int w = tid >> 6, lane = tid & 63;
    const int m = lane & 15, quad = lane >> 4;
    const int row0 = blockIdx.x << 6;
    int myrow = row0 + (w<<4) + m; if (myrow >= NND) myrow = NND-1;
    const unsigned short* hrow = hb + (size_t)myrow*128;
    short8v afr[4];
#pragma unroll
    for (int c=0;c<4;c++)
        afr[c] = *(const short8v*)(hrow + (c<<5) + (quad<<3));
    float4v zero = {0.f,0.f,0.f,0.f};
    float4v acc[8];
#pragma unroll
    for (int i=0;i<8;i++) acc[i] = zero;
#pragma unroll
    for (int c=0;c<4;c++){
#pragma unroll
        for (int ct=0;ct<8;ct++){
            short8v bf = *(const short8v*)(WoF + (((size_t)(c*8 + ct))*64 + lane)*8);
            acc[ct] = __builtin_amdgcn_mfma_f32_16x16x32_bf16(afr[c], bf, acc[ct], 0,0,0);
        }
    }
#pragma unroll
    for (int ct=0; ct<8; ct++){
        int col = (ct<<4) + m;
        float bb = bo[col];
#pragma unroll
        for (int r4=0; r4<4; r4++){
            int row = row0 + (w<<4) + (quad<<2) + r4;
            if (row < NND) out[(size_t)row*128 + col] = acc[ct][r4] + bb;
        }
    }
}

extern "C" void kernel_launch(void* const* d_in, const int* in_sizes, int n_in,
                              void* d_out, int out_size, void* d_ws, size_t ws_size,
                              hipStream_t stream)
{
    const float* node_attr = (const float*)d_in[0];
    const int*   edge_index= (const int*)  d_in[1];
    const float* noise = (const float*)d_in[3];
    const float* W1 = (const float*)d_in[4];
    const float* b1 = (const float*)d_in[5];
    const float* W2 = (const float*)d_in[6];
    const float* b2 = (const float*)d_in[7];
    const float* Wx = (const float*)d_in[8];
    const float* Wh = (const float*)d_in[9];
    const float* bx = (const float*)d_in[10];
    const float* bh = (const float*)d_in[11];
    const float* Wo = (const float*)d_in[12];
    const float* bo = (const float*)d_in[13];
    const int* dst = edge_index + (size_t)NND*DEG;
    float* out = (float*)d_out;
    if (ws_size < WS_NEED) return;

    char* ws = (char*)d_ws;
    float* hpre = (float*)(ws + OFF_HPRE);
    float* proj = (float*)(ws + OFF_PROJ);
    unsigned short* Xb  = (unsigned short*)(ws + OFF_XB);
    unsigned short* hbA = (unsigned short*)(ws + OFF_HBA);
    unsigned short* hbB = (unsigned short*)(ws + OFF_HBB);
    int* idxb = (int*)(ws + OFF_IDX);
    int* cur  = (int*)(ws + OFF_CUR);
    unsigned short* BqF = (unsigned short*)(ws + OFF_BQF);
    unsigned short* WoF = (unsigned short*)(ws + OFF_WOF);

    k_iota<<<dim3(196), dim3(256), 0, stream>>>(cur, idxb);
    k_pack_x  <<<dim3(6250), dim3(256), 0, stream>>>(node_attr, Xb);
    k_pack_bqf<<<dim3(512),  dim3(256), 0, stream>>>(Wx, Wh, BqF);
    k_pack_wof<<<dim3(64),   dim3(256), 0, stream>>>(Wo, WoF);

    // walk phase (fp32, bitwise-identical logits to split version)
    k_projall<<<dim3(782), dim3(256), 0, stream>>>(node_attr, W1, b1, hpre, proj);
    for (int t = 0; t < 4; t++){
        k_walk<<<dim3(3125), dim3(256), 0, stream>>>(hpre, proj + (size_t)t*NND*64,
                 dst, W2, b2, noise + (size_t)t*NND*DEG, cur, idxb + (size_t)(t+1)*NND);
    }
    // GRU: 5 barrier-free MFMA steps
    for (int s = 0; s < 5; s++){
        const unsigned short* hi = (s & 1) ? hbA : hbB;
        unsigned short*       ho = (s & 1) ? hbB : hbA;
        k_gruM<<<dim3(782), dim3(256), 0, stream>>>(hi, Xb, BqF, bx, bh,
                 idxb + (size_t)s*NND, ho, s == 0 ? 1 : 0);
    }
    k_outM<<<dim3(782), dim3(256), 0, stream>>>(hbA, WoF, bo, out);
}

// Round 5
// 565.494 us; speedup vs baseline: 1.2276x; 1.2276x over previous
//
#include <hip/hip_runtime.h>
#include <math.h>

#define NND 50000
#define DEG 16

typedef __attribute__((ext_vector_type(8))) short short8v;
typedef __attribute__((ext_vector_type(4))) float float4v;

// ---- workspace layout (bytes) ----
#define OFF_HPRE 0ULL            // N x 64 f32
#define OFF_PROJ 12800000ULL     // 4 x N x 64 f32
#define OFF_XB   64000000ULL     // N x 128 bf16
#define OFF_HBA  76800000ULL     // N x 128 bf16
#define OFF_HBB  89600000ULL     // N x 128 bf16
#define OFF_IDX  102400000ULL    // 5*N int
#define OFF_BQF  103600384ULL    // 4y x 8c x 8ct x 64 x 8 bf16 = 256 KB
#define OFF_WOF  103862528ULL    // 4c x 8ct x 64 x 8 bf16 = 32 KB
#define WS_NEED  103895296ULL

__device__ __forceinline__ float sigf(float x){ return 1.0f/(1.0f + expf(-x)); }
__device__ __forceinline__ unsigned short f2bf(float f){
    unsigned int u = __float_as_uint(f);
    u += 0x7FFFu + ((u >> 16) & 1u);
    return (unsigned short)(u >> 16);
}
__device__ __forceinline__ float bf2f(unsigned short h){
    return __uint_as_float(((unsigned int)h) << 16);
}

__global__ __launch_bounds__(256) void k_iota(int* __restrict__ idx0){
    int i = blockIdx.x*256 + threadIdx.x;
    if (i < NND) idx0[i] = i;
}

// ---------------- walk phase (fp32, argmax determinism) ----------------
// All 5 projections in one pass (unchanged from R4).
__global__ __launch_bounds__(256,2) void k_projall(const float* __restrict__ A,
    const float* __restrict__ W1, const float* __restrict__ b1,
    float* __restrict__ hpre, float* __restrict__ proj)
{
    __shared__ float Al[64][33];
    __shared__ float Bl[5][32][68];
    const int tid = threadIdx.x;
    const int row0 = blockIdx.x << 6;
    const int row_t = tid >> 4, col_t = tid & 15;
    float4 acc[5][4];
#pragma unroll
    for (int y=0;y<5;y++)
#pragma unroll
        for (int i=0;i<4;i++) acc[y][i] = make_float4(0.f,0.f,0.f,0.f);
    for (int k0 = 0; k0 < 128; k0 += 32){
#pragma unroll
        for (int r=0;r<2;r++){
            int am = (tid>>3) + (r<<5);
            int ak = (tid&7) << 2;
            int gr = row0 + am; if (gr >= NND) gr = NND-1;
            float4 v = *(const float4*)(A + (size_t)gr*128 + k0 + ak);
            Al[am][ak] = v.x; Al[am][ak+1] = v.y; Al[am][ak+2] = v.z; Al[am][ak+3] = v.w;
        }
#pragma unroll
        for (int r=0;r<10;r++){
            int p = (r<<8) + tid;
            int y = p >> 9, rem = p & 511;
            int bk = rem >> 4, bc = (rem & 15) << 2;
            *(float4*)(&Bl[y][bk][bc]) = *(const float4*)(W1 + ((size_t)(y*128 + k0 + bk))*64 + bc);
        }
        __syncthreads();
#pragma unroll 4
        for (int k=0;k<32;k++){
            float a[4];
#pragma unroll
            for (int i=0;i<4;i++) a[i] = Al[(row_t<<2)+i][k];
#pragma unroll
            for (int y=0;y<5;y++){
                float4 b = *(const float4*)(&Bl[y][k][col_t<<2]);
#pragma unroll
                for (int i=0;i<4;i++){
                    acc[y][i].x = fmaf(a[i], b.x, acc[y][i].x);
                    acc[y][i].y = fmaf(a[i], b.y, acc[y][i].y);
                    acc[y][i].z = fmaf(a[i], b.z, acc[y][i].z);
                    acc[y][i].w = fmaf(a[i], b.w, acc[y][i].w);
                }
            }
        }
        __syncthreads();
    }
    float4 bb = *(const float4*)(b1 + (col_t<<2));
#pragma unroll
    for (int y=0;y<5;y++){
        float* dst = (y == 0) ? hpre : (proj + (size_t)(y-1)*NND*64);
#pragma unroll
        for (int i=0;i<4;i++){
            int gr = row0 + (row_t<<2) + i;
            if (gr < NND){
                float4 o = acc[y][i];
                if (y == 0){ o.x += bb.x; o.y += bb.y; o.z += bb.z; o.w += bb.w; }
                *(float4*)(dst + (size_t)gr*64 + (col_t<<2)) = o;
            }
        }
    }
}

// All 4 walk steps fused; 16 lanes per node, lane l owns h-cols 4l..4l+3.
// Every proj row access is a coalesced 256B read; state in registers.
__global__ __launch_bounds__(256) void k_walk4(
    const float* __restrict__ hpre0, const float* __restrict__ proj,
    const int* __restrict__ dst, const float* __restrict__ W2,
    const float* __restrict__ b2, const float* __restrict__ noise,
    int* __restrict__ idxb)
{
    const int tid = threadIdx.x;
    const int sg = tid >> 4, l = tid & 15;
    const int gi = (blockIdx.x << 4) + sg;
    float4 hp = *(const float4*)(hpre0 + ((size_t)gi<<6) + (l<<2));
    float4 w2 = *(const float4*)(W2 + (l<<2));
    const float b2s = b2[0];
    int curv = gi;
#pragma unroll 1
    for (int t=0; t<4; t++){
        const float* pj = proj + (size_t)t*NND*64;
        const int nbr = dst[curv*DEG + l];
        float4 val[16];
#pragma unroll
        for (int d=0; d<16; d++){
            int nd = __shfl(nbr, d, 16);
            val[d] = *(const float4*)(pj + ((size_t)nd<<6) + (l<<2));
        }
        float lp = 0.f;
#pragma unroll
        for (int d=0; d<16; d++){
            float4 v = val[d];
            float q =  fmaxf(hp.x+v.x,0.f)*w2.x;
            q = fmaf(fmaxf(hp.y+v.y,0.f), w2.y, q);
            q = fmaf(fmaxf(hp.z+v.z,0.f), w2.z, q);
            q = fmaf(fmaxf(hp.w+v.w,0.f), w2.w, q);
            q += __shfl_xor(q, 1, 16);
            q += __shfl_xor(q, 2, 16);
            q += __shfl_xor(q, 4, 16);
            q += __shfl_xor(q, 8, 16);
            if (l == d) lp = q + b2s;
        }
        float mx = lp;
#pragma unroll
        for (int off=8; off; off>>=1) mx = fmaxf(mx, __shfl_xor(mx, off, 16));
        float s = expf(lp - mx);
#pragma unroll
        for (int off=8; off; off>>=1) s += __shfl_xor(s, off, 16);
        float p = expf(lp - mx - logf(s)) + noise[(size_t)t*NND*DEG + ((size_t)gi<<4) + l];
        float bv = p; int bi = l;
#pragma unroll
        for (int off=8; off; off>>=1){
            float ov = __shfl_xor(bv, off, 16);
            int   oi = __shfl_xor(bi, off, 16);
            if (ov > bv || (ov == bv && oi < bi)){ bv = ov; bi = oi; }
        }
        int sel = __shfl(nbr, bi, 16);
        if (l == 0) idxb[(size_t)(t+1)*NND + gi] = sel;
        float4 u = *(const float4*)(pj + ((size_t)sel<<6) + (l<<2));
        hp.x += u.x; hp.y += u.y; hp.z += u.z; hp.w += u.w;
        curv = sel;
    }
}

// ---------------- pack kernels ----------------
__global__ __launch_bounds__(256) void k_pack_x(const float* __restrict__ na,
    unsigned short* __restrict__ Xb)
{
    int i = blockIdx.x*256 + threadIdx.x;
    if (i < NND*32){
        float4 v = *(const float4*)(na + (size_t)i*4);
        unsigned long long pk = (unsigned long long)f2bf(v.x)
            | ((unsigned long long)f2bf(v.y) << 16)
            | ((unsigned long long)f2bf(v.z) << 32)
            | ((unsigned long long)f2bf(v.w) << 48);
        *(unsigned long long*)(Xb + (size_t)i*4) = pk;
    }
}

// BqF[y][c][ct][lane][8]: gate-blocked, MFMA-16x16x32 B-frag order (unchanged).
__global__ __launch_bounds__(256) void k_pack_bqf(const float* __restrict__ Wx,
    const float* __restrict__ Wh, unsigned short* __restrict__ BqF)
{
    int i = blockIdx.x*256 + threadIdx.x;  // 131072
    int jj = i & 7, lane = (i>>3)&63, ct = (i>>9)&7, c = (i>>12)&7, y = i>>15;
    int g = ct>>1, jh = ct&1, mm = lane&15, quad = lane>>4;
    int jg = (y<<5) + (jh<<4) + mm;
    int k = (c<<5) + (quad<<3) + jj;
    float v = 0.f;
    if (k < 128){
        if (g < 3) v = Wh[k*384 + g*128 + jg];
    } else {
        int kk = k - 128;
        if (g == 0)      v = Wx[kk*384 + jg];
        else if (g == 1) v = Wx[kk*384 + 128 + jg];
        else if (g == 3) v = Wx[kk*384 + 256 + jg];
    }
    BqF[i] = f2bf(v);
}

__global__ __launch_bounds__(256) void k_pack_wof(const float* __restrict__ Wo,
    unsigned short* __restrict__ WoF)
{
    int i = blockIdx.x*256 + threadIdx.x;  // 16384
    int jj = i & 7, lane = (i>>3)&63, ct = (i>>9)&7, c = i>>12;
    int n = (ct<<4) + (lane&15);
    int k = (c<<5) + ((lane>>4)<<3) + jj;
    WoF[i] = f2bf(Wo[k*128 + n]);
}

// ---------------- GRU step v5: 4 row-tiles/wave, A in LDS (1 barrier) ----------
// grid (782), block 256 = 4 waves. BM=64 rows shared; wave w = col-group y=w
// (128 packed cols, 8 ct). Each B-frag (1KB coalesced from L2-resident BqF)
// feeds 4 MFMAs -> L2 demand ~53 B/cyc/CU at full MFMA rate.
__global__ __launch_bounds__(256,2) void k_gruM(
    const unsigned short* __restrict__ hb_in,
    const unsigned short* __restrict__ Xb,
    const unsigned short* __restrict__ BqF,
    const float* __restrict__ bx, const float* __restrict__ bh,
    const int* __restrict__ xidx,
    unsigned short* __restrict__ hb_out, const int first)
{
    __shared__ unsigned short A_l[16384];  // [rt4][c8][lane64][8]
    const int tid = threadIdx.x;
    const int w = tid >> 6, lane = tid & 63;
    const int m = lane & 15, quad = lane >> 4;
    const int row0 = blockIdx.x << 6;
    // staging: thread (r = tid&63, q = tid>>6) covers row r, k-chunk q (h) and 4+q (x)
    const int r = tid & 63, q = tid >> 6;
    int gr = row0 + r; if (gr >= NND) gr = NND-1;
    const int xr = xidx[gr];
    const unsigned short* hrow = hb_in + (size_t)gr*128 + (q<<5);
    const unsigned short* xrow = Xb + (size_t)xr*128 + (q<<5);
    const int rt_s = r >> 4, m_s = r & 15;
#pragma unroll
    for (int u=0; u<4; u++){
        short8v hv;
        if (first){ short8v z = {0,0,0,0,0,0,0,0}; hv = z; }
        else hv = *(const short8v*)(hrow + (u<<3));
        short8v xv = *(const short8v*)(xrow + (u<<3));
        *(short8v*)(A_l + (((rt_s<<3) + q)*64 + (u<<4) + m_s)*8) = hv;
        *(short8v*)(A_l + (((rt_s<<3) + 4 + q)*64 + (u<<4) + m_s)*8) = xv;
    }
    __syncthreads();
    float4v zero = {0.f,0.f,0.f,0.f};
    float4v acc[32];                       // [ct][rt] -> acc[ct*4+rt]
#pragma unroll
    for (int i=0;i<32;i++) acc[i] = zero;
#pragma unroll 1
    for (int c=0;c<8;c++){
        short8v afr[4];
#pragma unroll
        for (int rt=0;rt<4;rt++)
            afr[rt] = *(const short8v*)(A_l + (((rt<<3) + c)*64 + lane)*8);
        const unsigned short* bp = BqF + (((((size_t)w<<3) + c)<<3)*64 + lane)*8;
#pragma unroll
        for (int ct=0;ct<8;ct++){
            short8v bf = *(const short8v*)(bp + (ct<<9));
#pragma unroll
            for (int rt=0;rt<4;rt++)
                acc[(ct<<2)+rt] = __builtin_amdgcn_mfma_f32_16x16x32_bf16(afr[rt], bf, acc[(ct<<2)+rt], 0,0,0);
        }
    }
    // in-lane epilogue: gates r,z,hn,xn at ct = g*2+jh, same lane
#pragma unroll
    for (int jh=0; jh<2; jh++){
        const int j = (w<<5) + (jh<<4) + m;
        const float brr = bx[j]       + bh[j];
        const float bzz = bx[128 + j] + bh[128 + j];
        const float bxn = bx[256 + j];
        const float bhn = bh[256 + j];
#pragma unroll
        for (int rt=0; rt<4; rt++){
#pragma unroll
            for (int r4=0; r4<4; r4++){
                int row = row0 + (rt<<4) + (quad<<2) + r4;
                if (row < NND){
                    float rg = sigf(acc[(jh<<2)+rt][r4] + brr);
                    float zg = sigf(acc[((2+jh)<<2)+rt][r4] + bzz);
                    float ng = tanhf(acc[((6+jh)<<2)+rt][r4] + bxn + rg*(acc[((4+jh)<<2)+rt][r4] + bhn));
                    float hpv = first ? 0.f : bf2f(hb_in[(size_t)row*128 + j]);
                    hb_out[(size_t)row*128 + j] = f2bf((1.f - zg)*ng + zg*hpv);
                }
            }
        }
    }
}

// out = hb @ Wo + bo: BM=256, 4 waves x 64 rows, all 128 cols, K=128.
__global__ __launch_bounds__(256,2) void k_outM(
    const unsigned short* __restrict__ hb,
    const unsigned short* __restrict__ WoF,
    const float* __restrict__ bo, float* __restrict__ out)
{
    __shared__ unsigned short A_l[32768];  // [rtile16][c4][lane64][8]
    const int tid = threadIdx.x;
    const int w = tid >> 6, lane = tid & 63;
    const int m = lane & 15, quad = lane >> 4;
    const int row0 = blockIdx.x << 8;
    int gr = row0 + tid; if (gr >= NND) gr = NND-1;
    const unsigned short* hrow = hb + (size_t)gr*128;
    const int rt_s = tid >> 4, m_s = tid & 15;
#pragma unroll
    for (int c=0; c<4; c++)
#pragma unroll
        for (int u=0; u<4; u++){
            short8v v = *(const short8v*)(hrow + (c<<5) + (u<<3));
            *(short8v*)(A_l + (((rt_s<<2) + c)*64 + (u<<4) + m_s)*8) = v;
        }
    __syncthreads();
    float4v zero = {0.f,0.f,0.f,0.f};
    float4v acc[32];
#pragma unroll
    for (int i=0;i<32;i++) acc[i] = zero;
#pragma unroll 1
    for (int c=0;c<4;c++){
        short8v afr[4];
#pragma unroll
        for (int rt=0;rt<4;rt++)
            afr[rt] = *(const short8v*)(A_l + (((((w<<2)+rt)<<2) + c)*64 + lane)*8);
#pragma unroll
        for (int ct=0;ct<8;ct++){
            short8v bf = *(const short8v*)(WoF + ((((c<<3)+ct)*64 + lane))*8);
#pragma unroll
            for (int rt=0;rt<4;rt++)
                acc[(ct<<2)+rt] = __builtin_amdgcn_mfma_f32_16x16x32_bf16(afr[rt], bf, acc[(ct<<2)+rt], 0,0,0);
        }
    }
#pragma unroll
    for (int ct=0; ct<8; ct++){
        int col = (ct<<4) + m;
        float bb = bo[col];
#pragma unroll
        for (int rt=0; rt<4; rt++){
#pragma unroll
            for (int r4=0; r4<4; r4++){
                int row = row0 + (w<<6) + (rt<<4) + (quad<<2) + r4;
                if (row < NND) out[(size_t)row*128 + col] = acc[(ct<<2)+rt][r4] + bb;
            }
        }
    }
}

extern "C" void kernel_launch(void* const* d_in, const int* in_sizes, int n_in,
                              void* d_out, int out_size, void* d_ws, size_t ws_size,
                              hipStream_t stream)
{
    const float* node_attr = (const float*)d_in[0];
    const int*   edge_index= (const int*)  d_in[1];
    const float* noise = (const float*)d_in[3];
    const float* W1 = (const float*)d_in[4];
    const float* b1 = (const float*)d_in[5];
    const float* W2 = (const float*)d_in[6];
    const float* b2 = (const float*)d_in[7];
    const float* Wx = (const float*)d_in[8];
    const float* Wh = (const float*)d_in[9];
    const float* bx = (const float*)d_in[10];
    const float* bh = (const float*)d_in[11];
    const float* Wo = (const float*)d_in[12];
    const float* bo = (const float*)d_in[13];
    const int* dst = edge_index + (size_t)NND*DEG;
    float* out = (float*)d_out;
    if (ws_size < WS_NEED) return;

    char* ws = (char*)d_ws;
    float* hpre = (float*)(ws + OFF_HPRE);
    float* proj = (float*)(ws + OFF_PROJ);
    unsigned short* Xb  = (unsigned short*)(ws + OFF_XB);
    unsigned short* hbA = (unsigned short*)(ws + OFF_HBA);
    unsigned short* hbB = (unsigned short*)(ws + OFF_HBB);
    int* idxb = (int*)(ws + OFF_IDX);
    unsigned short* BqF = (unsigned short*)(ws + OFF_BQF);
    unsigned short* WoF = (unsigned short*)(ws + OFF_WOF);

    k_iota<<<dim3(196), dim3(256), 0, stream>>>(idxb);
    k_pack_x  <<<dim3(6250), dim3(256), 0, stream>>>(node_attr, Xb);
    k_pack_bqf<<<dim3(512),  dim3(256), 0, stream>>>(Wx, Wh, BqF);
    k_pack_wof<<<dim3(64),   dim3(256), 0, stream>>>(Wo, WoF);

    // walk phase (fp32)
    k_projall<<<dim3(782), dim3(256), 0, stream>>>(node_attr, W1, b1, hpre, proj);
    k_walk4<<<dim3(3125), dim3(256), 0, stream>>>(hpre, proj, dst, W2, b2, noise, idxb);

    // GRU: 5 MFMA steps
    for (int s = 0; s < 5; s++){
        const unsigned short* hi = (s & 1) ? hbA : hbB;
        unsigned short*       ho = (s & 1) ? hbB : hbA;
        k_gruM<<<dim3(782), dim3(256), 0, stream>>>(hi, Xb, BqF, bx, bh,
                 idxb + (size_t)s*NND, ho, s == 0 ? 1 : 0);
    }
    k_outM<<<dim3(196), dim3(256), 0, stream>>>(hbA, WoF, bo, out);
}

// Round 6
// 474.238 us; speedup vs baseline: 1.4638x; 1.1924x over previous
//
#include <hip/hip_runtime.h>
#include <math.h>

#define NND 50000
#define DEG 16

typedef __attribute__((ext_vector_type(8))) short short8v;
typedef __attribute__((ext_vector_type(4))) float float4v;

// ---- workspace layout (bytes) ----
#define OFF_HPRE 0ULL            // N x 64 f32
#define OFF_PROJ 12800000ULL     // 4 x N x 64 f32
#define OFF_XB   64000000ULL     // N x 128 bf16
#define OFF_IDX  102400000ULL    // 5*N int
#define OFF_BQF  103600384ULL    // 4y x 8c x 8ct x 64 x 8 bf16 = 256 KB
#define OFF_WOF  103862528ULL    // 4c x 8ct x 64 x 8 bf16 = 32 KB
#define WS_NEED  103895296ULL

__device__ __forceinline__ float sigf(float x){ return 1.0f/(1.0f + expf(-x)); }
__device__ __forceinline__ unsigned short f2bf(float f){
    unsigned int u = __float_as_uint(f);
    u += 0x7FFFu + ((u >> 16) & 1u);
    return (unsigned short)(u >> 16);
}
__device__ __forceinline__ float bf2f(unsigned short h){
    return __uint_as_float(((unsigned int)h) << 16);
}

__global__ __launch_bounds__(256) void k_iota(int* __restrict__ idx0){
    int i = blockIdx.x*256 + threadIdx.x;
    if (i < NND) idx0[i] = i;
}

// ---------------- walk phase (fp32, argmax determinism) ----------------
// grid (782, 5): y-th 128-row block of W1; FMA order per output identical to
// the R1-R3 split kernels -> bitwise-identical logits.
__global__ __launch_bounds__(256) void k_projall(const float* __restrict__ A,
    const float* __restrict__ W1, const float* __restrict__ b1,
    float* __restrict__ hpre, float* __restrict__ proj)
{
    __shared__ float Al[64][33];
    __shared__ float Bl[32][68];
    const int tid = threadIdx.x;
    const int row0 = blockIdx.x << 6;
    const int y = blockIdx.y;
    const float* B = W1 + (size_t)y*128*64;
    const int row_t = tid >> 4, col_t = tid & 15;
    float4 acc[4];
#pragma unroll
    for (int i=0;i<4;i++) acc[i] = make_float4(0.f,0.f,0.f,0.f);
    for (int k0 = 0; k0 < 128; k0 += 32){
#pragma unroll
        for (int r=0;r<2;r++){
            int am = (tid>>3) + (r<<5);
            int ak = (tid&7) << 2;
            int gr = row0 + am; if (gr >= NND) gr = NND-1;
            float4 v = *(const float4*)(A + (size_t)gr*128 + k0 + ak);
            Al[am][ak] = v.x; Al[am][ak+1] = v.y; Al[am][ak+2] = v.z; Al[am][ak+3] = v.w;
        }
#pragma unroll
        for (int r=0;r<2;r++){
            int p = (r<<8) + tid;
            int bk = p >> 4, bc = (p & 15) << 2;
            *(float4*)(&Bl[bk][bc]) = *(const float4*)(B + (size_t)(k0+bk)*64 + bc);
        }
        __syncthreads();
#pragma unroll 8
        for (int k=0;k<32;k++){
            float4 b = *(const float4*)(&Bl[k][col_t<<2]);
#pragma unroll
            for (int i=0;i<4;i++){
                float a = Al[(row_t<<2)+i][k];
                acc[i].x = fmaf(a, b.x, acc[i].x);
                acc[i].y = fmaf(a, b.y, acc[i].y);
                acc[i].z = fmaf(a, b.z, acc[i].z);
                acc[i].w = fmaf(a, b.w, acc[i].w);
            }
        }
        __syncthreads();
    }
    float4 bb = make_float4(0.f,0.f,0.f,0.f);
    if (y == 0) bb = *(const float4*)(b1 + (col_t<<2));
    float* dst = (y == 0) ? hpre : (proj + (size_t)(y-1)*NND*64);
#pragma unroll
    for (int i=0;i<4;i++){
        int gr = row0 + (row_t<<2) + i;
        if (gr < NND){
            float4 o = make_float4(acc[i].x+bb.x, acc[i].y+bb.y, acc[i].z+bb.z, acc[i].w+bb.w);
            *(float4*)(dst + (size_t)gr*64 + (col_t<<2)) = o;
        }
    }
}

// All 4 walk steps fused; 16 lanes per node; coalesced 256B proj-row gathers.
__global__ __launch_bounds__(256) void k_walk4(
    const float* __restrict__ hpre0, const float* __restrict__ proj,
    const int* __restrict__ dst, const float* __restrict__ W2,
    const float* __restrict__ b2, const float* __restrict__ noise,
    int* __restrict__ idxb)
{
    const int tid = threadIdx.x;
    const int sg = tid >> 4, l = tid & 15;
    const int gi = (blockIdx.x << 4) + sg;
    float4 hp = *(const float4*)(hpre0 + ((size_t)gi<<6) + (l<<2));
    float4 w2 = *(const float4*)(W2 + (l<<2));
    const float b2s = b2[0];
    int curv = gi;
#pragma unroll 1
    for (int t=0; t<4; t++){
        const float* pj = proj + (size_t)t*NND*64;
        const int nbr = dst[curv*DEG + l];
        float4 val[16];
#pragma unroll
        for (int d=0; d<16; d++){
            int nd = __shfl(nbr, d, 16);
            val[d] = *(const float4*)(pj + ((size_t)nd<<6) + (l<<2));
        }
        float lp = 0.f;
#pragma unroll
        for (int d=0; d<16; d++){
            float4 v = val[d];
            float q =  fmaxf(hp.x+v.x,0.f)*w2.x;
            q = fmaf(fmaxf(hp.y+v.y,0.f), w2.y, q);
            q = fmaf(fmaxf(hp.z+v.z,0.f), w2.z, q);
            q = fmaf(fmaxf(hp.w+v.w,0.f), w2.w, q);
            q += __shfl_xor(q, 1, 16);
            q += __shfl_xor(q, 2, 16);
            q += __shfl_xor(q, 4, 16);
            q += __shfl_xor(q, 8, 16);
            if (l == d) lp = q + b2s;
        }
        float mx = lp;
#pragma unroll
        for (int off=8; off; off>>=1) mx = fmaxf(mx, __shfl_xor(mx, off, 16));
        float s = expf(lp - mx);
#pragma unroll
        for (int off=8; off; off>>=1) s += __shfl_xor(s, off, 16);
        float p = expf(lp - mx - logf(s)) + noise[(size_t)t*NND*DEG + ((size_t)gi<<4) + l];
        float bv = p; int bi = l;
#pragma unroll
        for (int off=8; off; off>>=1){
            float ov = __shfl_xor(bv, off, 16);
            int   oi = __shfl_xor(bi, off, 16);
            if (ov > bv || (ov == bv && oi < bi)){ bv = ov; bi = oi; }
        }
        int sel = __shfl(nbr, bi, 16);
        if (l == 0) idxb[(size_t)(t+1)*NND + gi] = sel;
        float4 u = *(const float4*)(pj + ((size_t)sel<<6) + (l<<2));
        hp.x += u.x; hp.y += u.y; hp.z += u.z; hp.w += u.w;
        curv = sel;
    }
}

// ---------------- pack kernels ----------------
__global__ __launch_bounds__(256) void k_pack_x(const float* __restrict__ na,
    unsigned short* __restrict__ Xb)
{
    int i = blockIdx.x*256 + threadIdx.x;
    if (i < NND*32){
        float4 v = *(const float4*)(na + (size_t)i*4);
        unsigned long long pk = (unsigned long long)f2bf(v.x)
            | ((unsigned long long)f2bf(v.y) << 16)
            | ((unsigned long long)f2bf(v.z) << 32)
            | ((unsigned long long)f2bf(v.w) << 48);
        *(unsigned long long*)(Xb + (size_t)i*4) = pk;
    }
}

// BqF[y][c][ct][lane][8]: gate-blocked, MFMA-16x16x32 B-frag order.
__global__ __launch_bounds__(256) void k_pack_bqf(const float* __restrict__ Wx,
    const float* __restrict__ Wh, unsigned short* __restrict__ BqF)
{
    int i = blockIdx.x*256 + threadIdx.x;  // 131072
    int jj = i & 7, lane = (i>>3)&63, ct = (i>>9)&7, c = (i>>12)&7, y = i>>15;
    int g = ct>>1, jh = ct&1, mm = lane&15, quad = lane>>4;
    int jg = (y<<5) + (jh<<4) + mm;
    int k = (c<<5) + (quad<<3) + jj;
    float v = 0.f;
    if (k < 128){
        if (g < 3) v = Wh[k*384 + g*128 + jg];
    } else {
        int kk = k - 128;
        if (g == 0)      v = Wx[kk*384 + jg];
        else if (g == 1) v = Wx[kk*384 + 128 + jg];
        else if (g == 3) v = Wx[kk*384 + 256 + jg];
    }
    BqF[i] = f2bf(v);
}

__global__ __launch_bounds__(256) void k_pack_wof(const float* __restrict__ Wo,
    unsigned short* __restrict__ WoF)
{
    int i = blockIdx.x*256 + threadIdx.x;  // 16384
    int jj = i & 7, lane = (i>>3)&63, ct = (i>>9)&7, c = i>>12;
    int n = (ct<<4) + (lane&15);
    int k = (c<<5) + ((lane>>4)<<3) + jj;
    WoF[i] = f2bf(Wo[k*128 + n]);
}

// ---------------- fully fused GRU (5 steps) + output GEMM ----------------
// grid (782), block 256 = 4 waves. Block owns 64 rows for the entire
// recurrence: h lives in LDS in MFMA A-frag layout [rt4][c4][64][8];
// epilogue writes h_new back into the same layout (bijective, per-thread
// disjoint). x gathered per step into X_l. Zero global h traffic.
__global__ __launch_bounds__(256,2) void k_gru5(
    const unsigned short* __restrict__ Xb,
    const unsigned short* __restrict__ BqF,
    const unsigned short* __restrict__ WoF,
    const float* __restrict__ bx, const float* __restrict__ bh,
    const float* __restrict__ bo, const int* __restrict__ idxb,
    float* __restrict__ out)
{
    __shared__ unsigned short A_l[8192];   // h  frags [rt4][c4][64][8]
    __shared__ unsigned short X_l[8192];   // x  frags [rt4][c4][64][8]
    const int tid = threadIdx.x;
    const int w = tid >> 6, lane = tid & 63;
    const int m = lane & 15, quad = lane >> 4;
    const int row0 = blockIdx.x << 6;
    // staging ids: thread (r, q) covers row r, x-chunk q
    const int r = tid & 63, q = tid >> 6;
    int gr = row0 + r; if (gr >= NND) gr = NND-1;
    const int rt_s = r >> 4, m_s = r & 15;
    // per-thread gate biases (cols j = (w<<5)+(jh<<4)+m)
    float brr[2], bzz[2], bxn[2], bhn[2];
#pragma unroll
    for (int jh=0; jh<2; jh++){
        int j = (w<<5) + (jh<<4) + m;
        brr[jh] = bx[j] + bh[j];
        bzz[jh] = bx[128+j] + bh[128+j];
        bxn[jh] = bx[256+j];
        bhn[jh] = bh[256+j];
    }
    // h_old/h_new LDS address for (jh, rt, r4): col j -> chunk w, unit (jh*2 + m/8)
    // addr = (((rt<<2)+w)*64 + (((jh<<1)+(m>>3))<<4) + (quad<<2)+r4)*8 + (m&7)
    const int hbase = (((((w)))*64 + ((((m>>3))<<4)) + (quad<<2))*8 + (m&7));

#pragma unroll 1
    for (int s=0; s<5; s++){
        // gather x rows for this step
        const int xr = idxb[(size_t)s*NND + gr];
        const unsigned short* xrow = Xb + (size_t)xr*128 + (q<<5);
        short8v xv[4];
#pragma unroll
        for (int u=0;u<4;u++) xv[u] = *(const short8v*)(xrow + (u<<3));
        __syncthreads();   // prev step's A_l writes done; prev X_l reads done
#pragma unroll
        for (int u=0;u<4;u++)
            *(short8v*)(X_l + (((rt_s<<2)+q)*64 + (u<<4) + m_s)*8) = xv[u];
        __syncthreads();   // X_l (and A_l) ready
        float4v zero = {0.f,0.f,0.f,0.f};
        float4v acc[32];   // [ct8][rt4]
#pragma unroll
        for (int i=0;i<32;i++) acc[i] = zero;
        const int c0 = (s == 0) ? 4 : 0;
#pragma unroll 1
        for (int c=c0;c<8;c++){
            const unsigned short* asrc = (c < 4) ? A_l : X_l;
            short8v afr[4];
#pragma unroll
            for (int rt=0;rt<4;rt++)
                afr[rt] = *(const short8v*)(asrc + (((rt<<2) + (c&3))*64 + lane)*8);
            const unsigned short* bp = BqF + ((((size_t)w*8 + c)*8)*64 + lane)*8;
#pragma unroll
            for (int ct=0;ct<8;ct++){
                short8v bf = *(const short8v*)(bp + (ct<<9));
#pragma unroll
                for (int rt=0;rt<4;rt++)
                    acc[(ct<<2)+rt] = __builtin_amdgcn_mfma_f32_16x16x32_bf16(afr[rt], bf, acc[(ct<<2)+rt], 0,0,0);
            }
        }
        // epilogue: compute h_new (reads h_old from A_l before any write)
        unsigned short hnew[2][4][4];
#pragma unroll
        for (int jh=0; jh<2; jh++){
#pragma unroll
            for (int rt=0; rt<4; rt++){
#pragma unroll
                for (int r4=0; r4<4; r4++){
                    int ha = ((((rt<<2)+w)*64 + (((jh<<1)+(m>>3))<<4) + (quad<<2)+r4)<<3) + (m&7);
                    float rg = sigf(acc[(jh<<2)+rt][r4] + brr[jh]);
                    float zg = sigf(acc[((2+jh)<<2)+rt][r4] + bzz[jh]);
                    float ng = tanhf(acc[((6+jh)<<2)+rt][r4] + bxn[jh] + rg*(acc[((4+jh)<<2)+rt][r4] + bhn[jh]));
                    float hold = (s == 0) ? 0.f : bf2f(A_l[ha]);
                    hnew[jh][rt][r4] = f2bf((1.f - zg)*ng + zg*hold);
                }
            }
        }
        __syncthreads();   // all A_l/X_l reads done
#pragma unroll
        for (int jh=0; jh<2; jh++)
#pragma unroll
            for (int rt=0; rt<4; rt++)
#pragma unroll
                for (int r4=0; r4<4; r4++){
                    int ha = ((((rt<<2)+w)*64 + (((jh<<1)+(m>>3))<<4) + (quad<<2)+r4)<<3) + (m&7);
                    A_l[ha] = hnew[jh][rt][r4];
                }
    }
    __syncthreads();
    // output GEMM: wave w -> cols (w<<5)..(w<<5)+31 (ct = 2w, 2w+1), K=128
    float4v zero = {0.f,0.f,0.f,0.f};
    float4v acco[8];   // [cto2][rt4]
#pragma unroll
    for (int i=0;i<8;i++) acco[i] = zero;
#pragma unroll 1
    for (int c=0;c<4;c++){
        short8v afr[4];
#pragma unroll
        for (int rt=0;rt<4;rt++)
            afr[rt] = *(const short8v*)(A_l + (((rt<<2) + c)*64 + lane)*8);
#pragma unroll
        for (int cto=0;cto<2;cto++){
            short8v bf = *(const short8v*)(WoF + (((size_t)(c*8 + (w<<1)+cto))*64 + lane)*8);
#pragma unroll
            for (int rt=0;rt<4;rt++)
                acco[(cto<<2)+rt] = __builtin_amdgcn_mfma_f32_16x16x32_bf16(afr[rt], bf, acco[(cto<<2)+rt], 0,0,0);
        }
    }
#pragma unroll
    for (int cto=0; cto<2; cto++){
        int col = (w<<5) + (cto<<4) + m;
        float bb = bo[col];
#pragma unroll
        for (int rt=0; rt<4; rt++){
#pragma unroll
            for (int r4=0; r4<4; r4++){
                int row = row0 + (rt<<4) + (quad<<2) + r4;
                if (row < NND) out[(size_t)row*128 + col] = acco[(cto<<2)+rt][r4] + bb;
            }
        }
    }
}

extern "C" void kernel_launch(void* const* d_in, const int* in_sizes, int n_in,
                              void* d_out, int out_size, void* d_ws, size_t ws_size,
                              hipStream_t stream)
{
    const float* node_attr = (const float*)d_in[0];
    const int*   edge_index= (const int*)  d_in[1];
    const float* noise = (const float*)d_in[3];
    const float* W1 = (const float*)d_in[4];
    const float* b1 = (const float*)d_in[5];
    const float* W2 = (const float*)d_in[6];
    const float* b2 = (const float*)d_in[7];
    const float* Wx = (const float*)d_in[8];
    const float* Wh = (const float*)d_in[9];
    const float* bx = (const float*)d_in[10];
    const float* bh = (const float*)d_in[11];
    const float* Wo = (const float*)d_in[12];
    const float* bo = (const float*)d_in[13];
    const int* dst = edge_index + (size_t)NND*DEG;
    float* out = (float*)d_out;
    if (ws_size < WS_NEED) return;

    char* ws = (char*)d_ws;
    float* hpre = (float*)(ws + OFF_HPRE);
    float* proj = (float*)(ws + OFF_PROJ);
    unsigned short* Xb  = (unsigned short*)(ws + OFF_XB);
    int* idxb = (int*)(ws + OFF_IDX);
    unsigned short* BqF = (unsigned short*)(ws + OFF_BQF);
    unsigned short* WoF = (unsigned short*)(ws + OFF_WOF);

    k_iota<<<dim3(196), dim3(256), 0, stream>>>(idxb);
    k_pack_x  <<<dim3(6250), dim3(256), 0, stream>>>(node_attr, Xb);
    k_pack_bqf<<<dim3(512),  dim3(256), 0, stream>>>(Wx, Wh, BqF);
    k_pack_wof<<<dim3(64),   dim3(256), 0, stream>>>(Wo, WoF);

    // walk phase (fp32)
    k_projall<<<dim3(782, 5), dim3(256), 0, stream>>>(node_attr, W1, b1, hpre, proj);
    k_walk4<<<dim3(3125), dim3(256), 0, stream>>>(hpre, proj, dst, W2, b2, noise, idxb);

    // GRU (all 5 steps) + output GEMM, one kernel
    k_gru5<<<dim3(782), dim3(256), 0, stream>>>(Xb, BqF, WoF, bx, bh, bo, idxb, out);
}

// Round 7
// 386.227 us; speedup vs baseline: 1.7973x; 1.2279x over previous
//
#include <hip/hip_runtime.h>
#include <math.h>

#define NND 50000
#define DEG 16

typedef __attribute__((ext_vector_type(8))) short short8v;
typedef __attribute__((ext_vector_type(4))) float float4v;

// ---- workspace layout (bytes) ----
#define OFF_HPRE 0ULL            // N x 64 f32
#define OFF_PROJ 12800000ULL     // 4 x N x 64 f32
#define OFF_XB   64000000ULL     // N x 128 bf16
#define OFF_IDX  102400000ULL    // 5*N int
#define OFF_BQF  103600384ULL    // 4y x 8c x 8ct x 64 x 8 bf16 = 256 KB
#define OFF_WOF  103862528ULL    // 4c x 8ct x 64 x 8 bf16 = 32 KB
#define WS_NEED  103895296ULL

#define LOG2E 1.44269504088896f

__device__ __forceinline__ float fast_sig(float x){
    return __builtin_amdgcn_rcpf(1.f + __builtin_amdgcn_exp2f(-LOG2E*x));
}
__device__ __forceinline__ float fast_tanh(float x){
    return fmaf(-2.f, __builtin_amdgcn_rcpf(1.f + __builtin_amdgcn_exp2f((2.f*LOG2E)*x)), 1.f);
}
__device__ __forceinline__ unsigned short f2bf(float f){
    unsigned int u = __float_as_uint(f);
    u += 0x7FFFu + ((u >> 16) & 1u);
    return (unsigned short)(u >> 16);
}
__device__ __forceinline__ float bf2f(unsigned short h){
    return __uint_as_float(((unsigned int)h) << 16);
}

__global__ __launch_bounds__(256) void k_iota(int* __restrict__ idx0){
    int i = blockIdx.x*256 + threadIdx.x;
    if (i < NND) idx0[i] = i;
}

// ---------------- walk phase (fp32, argmax determinism) ----------------
__global__ __launch_bounds__(256) void k_projall(const float* __restrict__ A,
    const float* __restrict__ W1, const float* __restrict__ b1,
    float* __restrict__ hpre, float* __restrict__ proj)
{
    __shared__ float Al[64][33];
    __shared__ float Bl[32][68];
    const int tid = threadIdx.x;
    const int row0 = blockIdx.x << 6;
    const int y = blockIdx.y;
    const float* B = W1 + (size_t)y*128*64;
    const int row_t = tid >> 4, col_t = tid & 15;
    float4 acc[4];
#pragma unroll
    for (int i=0;i<4;i++) acc[i] = make_float4(0.f,0.f,0.f,0.f);
    for (int k0 = 0; k0 < 128; k0 += 32){
#pragma unroll
        for (int r=0;r<2;r++){
            int am = (tid>>3) + (r<<5);
            int ak = (tid&7) << 2;
            int gr = row0 + am; if (gr >= NND) gr = NND-1;
            float4 v = *(const float4*)(A + (size_t)gr*128 + k0 + ak);
            Al[am][ak] = v.x; Al[am][ak+1] = v.y; Al[am][ak+2] = v.z; Al[am][ak+3] = v.w;
        }
#pragma unroll
        for (int r=0;r<2;r++){
            int p = (r<<8) + tid;
            int bk = p >> 4, bc = (p & 15) << 2;
            *(float4*)(&Bl[bk][bc]) = *(const float4*)(B + (size_t)(k0+bk)*64 + bc);
        }
        __syncthreads();
#pragma unroll 8
        for (int k=0;k<32;k++){
            float4 b = *(const float4*)(&Bl[k][col_t<<2]);
#pragma unroll
            for (int i=0;i<4;i++){
                float a = Al[(row_t<<2)+i][k];
                acc[i].x = fmaf(a, b.x, acc[i].x);
                acc[i].y = fmaf(a, b.y, acc[i].y);
                acc[i].z = fmaf(a, b.z, acc[i].z);
                acc[i].w = fmaf(a, b.w, acc[i].w);
            }
        }
        __syncthreads();
    }
    float4 bb = make_float4(0.f,0.f,0.f,0.f);
    if (y == 0) bb = *(const float4*)(b1 + (col_t<<2));
    float* dst = (y == 0) ? hpre : (proj + (size_t)(y-1)*NND*64);
#pragma unroll
    for (int i=0;i<4;i++){
        int gr = row0 + (row_t<<2) + i;
        if (gr < NND){
            float4 o = make_float4(acc[i].x+bb.x, acc[i].y+bb.y, acc[i].z+bb.z, acc[i].w+bb.w);
            *(float4*)(dst + (size_t)gr*64 + (col_t<<2)) = o;
        }
    }
}

// All 4 walk steps fused; 16 lanes per node; coalesced 256B proj-row gathers.
__global__ __launch_bounds__(256) void k_walk4(
    const float* __restrict__ hpre0, const float* __restrict__ proj,
    const int* __restrict__ dst, const float* __restrict__ W2,
    const float* __restrict__ b2, const float* __restrict__ noise,
    int* __restrict__ idxb)
{
    const int tid = threadIdx.x;
    const int sg = tid >> 4, l = tid & 15;
    const int gi = (blockIdx.x << 4) + sg;
    float4 hp = *(const float4*)(hpre0 + ((size_t)gi<<6) + (l<<2));
    float4 w2 = *(const float4*)(W2 + (l<<2));
    const float b2s = b2[0];
    int curv = gi;
#pragma unroll 1
    for (int t=0; t<4; t++){
        const float* pj = proj + (size_t)t*NND*64;
        const int nbr = dst[curv*DEG + l];
        float4 val[16];
#pragma unroll
        for (int d=0; d<16; d++){
            int nd = __shfl(nbr, d, 16);
            val[d] = *(const float4*)(pj + ((size_t)nd<<6) + (l<<2));
        }
        float lp = 0.f;
#pragma unroll
        for (int d=0; d<16; d++){
            float4 v = val[d];
            float q =  fmaxf(hp.x+v.x,0.f)*w2.x;
            q = fmaf(fmaxf(hp.y+v.y,0.f), w2.y, q);
            q = fmaf(fmaxf(hp.z+v.z,0.f), w2.z, q);
            q = fmaf(fmaxf(hp.w+v.w,0.f), w2.w, q);
            q += __shfl_xor(q, 1, 16);
            q += __shfl_xor(q, 2, 16);
            q += __shfl_xor(q, 4, 16);
            q += __shfl_xor(q, 8, 16);
            if (l == d) lp = q + b2s;
        }
        float mx = lp;
#pragma unroll
        for (int off=8; off; off>>=1) mx = fmaxf(mx, __shfl_xor(mx, off, 16));
        float s = expf(lp - mx);
#pragma unroll
        for (int off=8; off; off>>=1) s += __shfl_xor(s, off, 16);
        float p = expf(lp - mx - logf(s)) + noise[(size_t)t*NND*DEG + ((size_t)gi<<4) + l];
        float bv = p; int bi = l;
#pragma unroll
        for (int off=8; off; off>>=1){
            float ov = __shfl_xor(bv, off, 16);
            int   oi = __shfl_xor(bi, off, 16);
            if (ov > bv || (ov == bv && oi < bi)){ bv = ov; bi = oi; }
        }
        int sel = __shfl(nbr, bi, 16);
        if (l == 0) idxb[(size_t)(t+1)*NND + gi] = sel;
        float4 u = *(const float4*)(pj + ((size_t)sel<<6) + (l<<2));
        hp.x += u.x; hp.y += u.y; hp.z += u.z; hp.w += u.w;
        curv = sel;
    }
}

// ---------------- pack kernels ----------------
__global__ __launch_bounds__(256) void k_pack_x(const float* __restrict__ na,
    unsigned short* __restrict__ Xb)
{
    int i = blockIdx.x*256 + threadIdx.x;
    if (i < NND*32){
        float4 v = *(const float4*)(na + (size_t)i*4);
        unsigned long long pk = (unsigned long long)f2bf(v.x)
            | ((unsigned long long)f2bf(v.y) << 16)
            | ((unsigned long long)f2bf(v.z) << 32)
            | ((unsigned long long)f2bf(v.w) << 48);
        *(unsigned long long*)(Xb + (size_t)i*4) = pk;
    }
}

__global__ __launch_bounds__(256) void k_pack_bqf(const float* __restrict__ Wx,
    const float* __restrict__ Wh, unsigned short* __restrict__ BqF)
{
    int i = blockIdx.x*256 + threadIdx.x;  // 131072
    int jj = i & 7, lane = (i>>3)&63, ct = (i>>9)&7, c = (i>>12)&7, y = i>>15;
    int g = ct>>1, jh = ct&1, mm = lane&15, quad = lane>>4;
    int jg = (y<<5) + (jh<<4) + mm;
    int k = (c<<5) + (quad<<3) + jj;
    float v = 0.f;
    if (k < 128){
        if (g < 3) v = Wh[k*384 + g*128 + jg];
    } else {
        int kk = k - 128;
        if (g == 0)      v = Wx[kk*384 + jg];
        else if (g == 1) v = Wx[kk*384 + 128 + jg];
        else if (g == 3) v = Wx[kk*384 + 256 + jg];
    }
    BqF[i] = f2bf(v);
}

__global__ __launch_bounds__(256) void k_pack_wof(const float* __restrict__ Wo,
    unsigned short* __restrict__ WoF)
{
    int i = blockIdx.x*256 + threadIdx.x;  // 16384
    int jj = i & 7, lane = (i>>3)&63, ct = (i>>9)&7, c = i>>12;
    int n = (ct<<4) + (lane&15);
    int k = (c<<5) + ((lane>>4)<<3) + jj;
    WoF[i] = f2bf(Wo[k*128 + n]);
}

// ---------------- fully fused GRU (5 steps) + output GEMM, v2 ----------------
// 64 rows/block for the whole recurrence. h frags in A_l; x double-buffered
// (X_l parity => race-free writes with 2 barriers/step); h_old carried in
// registers (no scattered LDS reads); native exp2/rcp gate math.
__global__ __launch_bounds__(256,2) void k_gru5(
    const unsigned short* __restrict__ Xb,
    const unsigned short* __restrict__ BqF,
    const unsigned short* __restrict__ WoF,
    const float* __restrict__ bx, const float* __restrict__ bh,
    const float* __restrict__ bo, const int* __restrict__ idxb,
    float* __restrict__ out)
{
    __shared__ unsigned short A_l[8192];    // h frags [rt4][c4][64][8]
    __shared__ unsigned short X_l[16384];   // x frags, 2 buffers of 8192
    const int tid = threadIdx.x;
    const int w = tid >> 6, lane = tid & 63;
    const int m = lane & 15, quad = lane >> 4;
    const int row0 = blockIdx.x << 6;
    const int r = tid & 63, q = tid >> 6;
    int gr = row0 + r; if (gr >= NND) gr = NND-1;
    const int rt_s = r >> 4, m_s = r & 15;
    // per-thread gate biases (cols j = (w<<5)+(jh<<4)+m)
    float brr[2], bzz[2], bxn[2], bhn[2];
#pragma unroll
    for (int jh=0; jh<2; jh++){
        int j = (w<<5) + (jh<<4) + m;
        brr[jh] = bx[j] + bh[j];
        bzz[jh] = bx[128+j] + bh[128+j];
        bxn[jh] = bx[256+j];
        bhn[jh] = bh[256+j];
    }
    // h_old carried in regs as packed bf16 [jh][rt][r4]
    unsigned short holdv[2][4][4];
    // prefetch x_0, stage, prefetch x_1
    short8v xv[4];
    {
        const int xr = idxb[gr];
        const unsigned short* xrow = Xb + (size_t)xr*128 + (q<<5);
#pragma unroll
        for (int u=0;u<4;u++) xv[u] = *(const short8v*)(xrow + (u<<3));
#pragma unroll
        for (int u=0;u<4;u++)
            *(short8v*)(X_l + (((rt_s<<2)+q)*64 + (u<<4) + m_s)*8) = xv[u];
        const int xr1 = idxb[NND + gr];
        const unsigned short* xrow1 = Xb + (size_t)xr1*128 + (q<<5);
#pragma unroll
        for (int u=0;u<4;u++) xv[u] = *(const short8v*)(xrow1 + (u<<3));
    }
    __syncthreads();

#pragma unroll 1
    for (int s=0; s<5; s++){
        const unsigned short* Xcur = X_l + ((s&1)<<13);
        float4v zero = {0.f,0.f,0.f,0.f};
        float4v acc[32];   // [ct8][rt4]
#pragma unroll
        for (int i=0;i<32;i++) acc[i] = zero;
        const int c0 = (s == 0) ? 4 : 0;
        for (int c=c0;c<8;c++){
            const unsigned short* asrc = (c < 4) ? A_l : Xcur;
            short8v afr[4];
#pragma unroll
            for (int rt=0;rt<4;rt++)
                afr[rt] = *(const short8v*)(asrc + (((rt<<2) + (c&3))*64 + lane)*8);
            const unsigned short* bp = BqF + ((((size_t)w*8 + c)*8)*64 + lane)*8;
#pragma unroll
            for (int ct=0;ct<8;ct++){
                short8v bf = *(const short8v*)(bp + (ct<<9));
#pragma unroll
                for (int rt=0;rt<4;rt++)
                    acc[(ct<<2)+rt] = __builtin_amdgcn_mfma_f32_16x16x32_bf16(afr[rt], bf, acc[(ct<<2)+rt], 0,0,0);
            }
        }
        // stage x_{s+1} into the other buffer; prefetch x_{s+2}
        if (s < 4){
            unsigned short* Xnxt = X_l + (((s+1)&1)<<13);
#pragma unroll
            for (int u=0;u<4;u++)
                *(short8v*)(Xnxt + (((rt_s<<2)+q)*64 + (u<<4) + m_s)*8) = xv[u];
            if (s < 3){
                const int xr = idxb[(size_t)(s+2)*NND + gr];
                const unsigned short* xrow = Xb + (size_t)xr*128 + (q<<5);
#pragma unroll
                for (int u=0;u<4;u++) xv[u] = *(const short8v*)(xrow + (u<<3));
            }
        }
        // epilogue: fast gates, h_old from regs
#pragma unroll
        for (int jh=0; jh<2; jh++){
#pragma unroll
            for (int rt=0; rt<4; rt++){
#pragma unroll
                for (int r4=0; r4<4; r4++){
                    float rg = fast_sig(acc[(jh<<2)+rt][r4] + brr[jh]);
                    float zg = fast_sig(acc[((2+jh)<<2)+rt][r4] + bzz[jh]);
                    float ng = fast_tanh(acc[((6+jh)<<2)+rt][r4] + bxn[jh] + rg*(acc[((4+jh)<<2)+rt][r4] + bhn[jh]));
                    float hold = (s == 0) ? 0.f : bf2f(holdv[jh][rt][r4]);
                    holdv[jh][rt][r4] = f2bf((1.f - zg)*ng + zg*hold);
                }
            }
        }
        __syncthreads();   // all A_l/X_l reads of this step done
#pragma unroll
        for (int jh=0; jh<2; jh++)
#pragma unroll
            for (int rt=0; rt<4; rt++)
#pragma unroll
                for (int r4=0; r4<4; r4++){
                    int ha = ((((rt<<2)+w)*64 + (((jh<<1)+(m>>3))<<4) + (quad<<2)+r4)<<3) + (m&7);
                    A_l[ha] = holdv[jh][rt][r4];
                }
        __syncthreads();   // A_l ready for next step / out-GEMM
    }
    // output GEMM: wave w -> cols (w<<5)..(w<<5)+31, K=128
    float4v zero = {0.f,0.f,0.f,0.f};
    float4v acco[8];   // [cto2][rt4]
#pragma unroll
    for (int i=0;i<8;i++) acco[i] = zero;
    for (int c=0;c<4;c++){
        short8v afr[4];
#pragma unroll
        for (int rt=0;rt<4;rt++)
            afr[rt] = *(const short8v*)(A_l + (((rt<<2) + c)*64 + lane)*8);
#pragma unroll
        for (int cto=0;cto<2;cto++){
            short8v bf = *(const short8v*)(WoF + (((size_t)(c*8 + (w<<1)+cto))*64 + lane)*8);
#pragma unroll
            for (int rt=0;rt<4;rt++)
                acco[(cto<<2)+rt] = __builtin_amdgcn_mfma_f32_16x16x32_bf16(afr[rt], bf, acco[(cto<<2)+rt], 0,0,0);
        }
    }
#pragma unroll
    for (int cto=0; cto<2; cto++){
        int col = (w<<5) + (cto<<4) + m;
        float bb = bo[col];
#pragma unroll
        for (int rt=0; rt<4; rt++){
#pragma unroll
            for (int r4=0; r4<4; r4++){
                int row = row0 + (rt<<4) + (quad<<2) + r4;
                if (row < NND) out[(size_t)row*128 + col] = acco[(cto<<2)+rt][r4] + bb;
            }
        }
    }
}

extern "C" void kernel_launch(void* const* d_in, const int* in_sizes, int n_in,
                              void* d_out, int out_size, void* d_ws, size_t ws_size,
                              hipStream_t stream)
{
    const float* node_attr = (const float*)d_in[0];
    const int*   edge_index= (const int*)  d_in[1];
    const float* noise = (const float*)d_in[3];
    const float* W1 = (const float*)d_in[4];
    const float* b1 = (const float*)d_in[5];
    const float* W2 = (const float*)d_in[6];
    const float* b2 = (const float*)d_in[7];
    const float* Wx = (const float*)d_in[8];
    const float* Wh = (const float*)d_in[9];
    const float* bx = (const float*)d_in[10];
    const float* bh = (const float*)d_in[11];
    const float* Wo = (const float*)d_in[12];
    const float* bo = (const float*)d_in[13];
    const int* dst = edge_index + (size_t)NND*DEG;
    float* out = (float*)d_out;
    if (ws_size < WS_NEED) return;

    char* ws = (char*)d_ws;
    float* hpre = (float*)(ws + OFF_HPRE);
    float* proj = (float*)(ws + OFF_PROJ);
    unsigned short* Xb  = (unsigned short*)(ws + OFF_XB);
    int* idxb = (int*)(ws + OFF_IDX);
    unsigned short* BqF = (unsigned short*)(ws + OFF_BQF);
    unsigned short* WoF = (unsigned short*)(ws + OFF_WOF);

    k_iota<<<dim3(196), dim3(256), 0, stream>>>(idxb);
    k_pack_x  <<<dim3(6250), dim3(256), 0, stream>>>(node_attr, Xb);
    k_pack_bqf<<<dim3(512),  dim3(256), 0, stream>>>(Wx, Wh, BqF);
    k_pack_wof<<<dim3(64),   dim3(256), 0, stream>>>(Wo, WoF);

    // walk phase (fp32)
    k_projall<<<dim3(782, 5), dim3(256), 0, stream>>>(node_attr, W1, b1, hpre, proj);
    k_walk4<<<dim3(3125), dim3(256), 0, stream>>>(hpre, proj, dst, W2, b2, noise, idxb);

    // GRU (all 5 steps) + output GEMM, one kernel
    k_gru5<<<dim3(782), dim3(256), 0, stream>>>(Xb, BqF, WoF, bx, bh, bo, idxb, out);
}